// Round 2
// baseline (571.225 us; speedup 1.0000x reference)
//
#include <hip/hip_runtime.h>
#include <hip/hip_bf16.h>

#define LOG2E 1.4426950408889634f
#define LN2   0.6931471805599453f

typedef __attribute__((ext_vector_type(8))) short short8;
typedef __attribute__((ext_vector_type(4))) float f32x4;

#define B_ 8
#define N_ 128
#define M_ 32
#define C_ 65536
#define KCHUNKS 64
#define KC (C_ / KCHUNKS)   // 1024
#define BK 64
#define AST 72              // LDS row stride in bf16 elems (144B: 16B-aligned)

// Native bf16 RNE casts: compiler emits the efficient cvt sequence (m240:
// plain casts beat both manual integer-RNE and hand-written cvt_pk asm).
__device__ __forceinline__ unsigned pack2(float lo, float hi) {
  union { __hip_bfloat16 h; unsigned short s; } a, b;
  a.h = __float2bfloat16(lo);
  b.h = __float2bfloat16(hi);
  return (unsigned)a.s | ((unsigned)b.s << 16);
}

// 512 blocks (64 k-chunks x 8 batches) x 256 threads, 2 blocks/CU.
// Fused: pred tile -> x,sigmoid,softplus -> bf16 LDS -> MFMA vs gt tile.
// NO atomics: every block writes its partials to a private ws slice.
// Register double-buffer of global loads: next k-step's 10x float4 issued
// before current compute, consumed after 2nd barrier, so HBM stays
// saturated across the compute/MFMA/barrier phases.
__global__ __launch_bounds__(256, 2) void cost_partial_kernel(
    const float* __restrict__ pred, const float* __restrict__ gt,
    float* __restrict__ xg_part, float* __restrict__ sg_part,
    float* __restrict__ sp_part, float* __restrict__ ss_part,
    float* __restrict__ gts_part)
{
  __shared__ unsigned short As[256 * AST];  // rows 0..127: x, 128..255: sigmoid
  __shared__ unsigned short Bt[32 * AST];   // gt tile
  const int kc = blockIdx.x, b = blockIdx.y;
  const int tid = threadIdx.x;
  const int grp = tid >> 4, gl = tid & 15;   // pred: 16 rows/pass, 16 thr/row
  const int grow = tid >> 3, gh = tid & 7;   // gt: 32 rows, 8 thr/row
  const int wave = tid >> 6, lane = tid & 63;
  const int quad = lane >> 4, lcol = lane & 15;
  const int c0 = kc * KC;
  const int slab = kc * B_ + b;              // this block's partial slot

  const float* predB = pred + (size_t)b * N_ * C_ + c0;
  const float* gtB   = gt   + (size_t)b * M_ * C_ + (size_t)grow * C_ + c0;

  float spr[8], sr[8], gtacc = 0.f;
#pragma unroll
  for (int r = 0; r < 8; ++r) { spr[r] = 0.f; sr[r] = 0.f; }

  f32x4 acc[4][2];
#pragma unroll
  for (int rt = 0; rt < 4; ++rt)
#pragma unroll
    for (int ct = 0; ct < 2; ++ct)
      acc[rt][ct] = (f32x4){0.f, 0.f, 0.f, 0.f};

  // ---- prefetch k-step 0 into registers ----
  float4 p[8], g0, g1;
#pragma unroll
  for (int r = 0; r < 8; ++r)
    p[r] = *(const float4*)(predB + (size_t)(r * 16 + grp) * C_ + gl * 4);
  g0 = *(const float4*)(gtB + gh * 4);
  g1 = *(const float4*)(gtB + (gh + 8) * 4);

  for (int ks = 0; ks < KC / BK; ++ks) {
    // ---- issue next k-step's loads NOW; they drain during compute+MFMA ----
    float4 pn[8], gn0, gn1;
    if (ks + 1 < KC / BK) {
      const int cb = (ks + 1) * BK;
#pragma unroll
      for (int r = 0; r < 8; ++r)
        pn[r] = *(const float4*)(predB + (size_t)(r * 16 + grp) * C_ + cb + gl * 4);
      gn0 = *(const float4*)(gtB + cb + gh * 4);
      gn1 = *(const float4*)(gtB + cb + (gh + 8) * 4);
    }

    // ---- compute phase on current tile (already in registers) ----
#pragma unroll
    for (int r = 0; r < 8; ++r) {
      const int row = r * 16 + grp;
      float xs[4] = {p[r].x, p[r].y, p[r].z, p[r].w};
      float ss[4];
#pragma unroll
      for (int e = 0; e < 4; ++e) {
        float x = xs[e];
        // exp2 of large-negative is a clean 0 -> only guard +inf side
        float t = fminf(x * LOG2E, 80.f);
        float e2 = __builtin_amdgcn_exp2f(t);
        float z = 1.f + e2;
        float s = e2 * __builtin_amdgcn_rcpf(z);
        spr[r] += __builtin_amdgcn_logf(z);   // accumulate log2; scale LN2 at end
        sr[r]  += s;
        ss[e] = s;
      }
      *(uint2*)&As[row * AST + gl * 4] =
          (uint2){pack2(xs[0], xs[1]), pack2(xs[2], xs[3])};
      *(uint2*)&As[(N_ + row) * AST + gl * 4] =
          (uint2){pack2(ss[0], ss[1]), pack2(ss[2], ss[3])};
    }
    gtacc += g0.x + g0.y + g0.z + g0.w + g1.x + g1.y + g1.z + g1.w;
    *(uint2*)&Bt[grow * AST + gh * 4] =
        (uint2){pack2(g0.x, g0.y), pack2(g0.z, g0.w)};
    *(uint2*)&Bt[grow * AST + (gh + 8) * 4] =
        (uint2){pack2(g1.x, g1.y), pack2(g1.z, g1.w)};
    __syncthreads();

#pragma unroll
    for (int k0 = 0; k0 < BK; k0 += 32) {
      const int koff = k0 + quad * 8;
      short8 bf0 = *(const short8*)&Bt[lcol * AST + koff];
      short8 bf1 = *(const short8*)&Bt[(16 + lcol) * AST + koff];
#pragma unroll
      for (int rt = 0; rt < 4; ++rt) {
        short8 af = *(const short8*)&As[(wave * 64 + rt * 16 + lcol) * AST + koff];
        acc[rt][0] = __builtin_amdgcn_mfma_f32_16x16x32_bf16(af, bf0, acc[rt][0], 0, 0, 0);
        acc[rt][1] = __builtin_amdgcn_mfma_f32_16x16x32_bf16(af, bf1, acc[rt][1], 0, 0, 0);
      }
    }
    __syncthreads();

    // ---- consume prefetch (compiler renames; waitcnt lands here, after MFMA) ----
    if (ks + 1 < KC / BK) {
#pragma unroll
      for (int r = 0; r < 8; ++r) p[r] = pn[r];
      g0 = gn0; g1 = gn1;
    }
  }

  // per-row sums: 16 consecutive lanes share a pred row
#pragma unroll
  for (int r = 0; r < 8; ++r) {
    float v1 = spr[r], v2 = sr[r];
#pragma unroll
    for (int off = 1; off < 16; off <<= 1) {
      v1 += __shfl_xor(v1, off);
      v2 += __shfl_xor(v2, off);
    }
    if (gl == 0) {
      sp_part[slab * N_ + r * 16 + grp] = v1 * LN2;  // deferred softplus scale
      ss_part[slab * N_ + r * 16 + grp] = v2;
    }
  }
  gtacc += __shfl_xor(gtacc, 1);
  gtacc += __shfl_xor(gtacc, 2);
  gtacc += __shfl_xor(gtacc, 4);
  if (gh == 0) gts_part[slab * M_ + grow] = gtacc;

  // GEMM partials, plain stores: C/D layout col=lane&15, row=(lane>>4)*4+reg
#pragma unroll
  for (int rt = 0; rt < 4; ++rt)
#pragma unroll
    for (int ct = 0; ct < 2; ++ct)
#pragma unroll
      for (int reg = 0; reg < 4; ++reg) {
        int orow = wave * 64 + rt * 16 + quad * 4 + reg;   // 0..255
        int ocol = ct * 16 + lcol;
        float v = acc[rt][ct][reg];
        if (orow < N_) xg_part[(slab * N_ + orow) * M_ + ocol] = v;
        else           sg_part[(slab * N_ + (orow - N_)) * M_ + ocol] = v;
      }
}

__global__ void finalize_kernel(const float* __restrict__ obj,
    const float* __restrict__ xg_part, const float* __restrict__ sg_part,
    const float* __restrict__ sp_part, const float* __restrict__ ss_part,
    const float* __restrict__ gts_part, float* __restrict__ cost)
{
  int idx = blockIdx.x * blockDim.x + threadIdx.x;  // [0, 32768)
  int b = idx >> 12;
  int n = (idx >> 5) & 127;
  int m = idx & 31;
  float xa = 0.f, sa = 0.f, spa = 0.f, ssa = 0.f, ga = 0.f;
#pragma unroll 4
  for (int kc = 0; kc < KCHUNKS; ++kc) {
    int slab = kc * B_ + b;
    xa  += xg_part[(slab * N_ + n) * M_ + m];
    sa  += sg_part[(slab * N_ + n) * M_ + m];
    spa += sp_part[slab * N_ + n];
    ssa += ss_part[slab * N_ + n];
    ga  += gts_part[slab * M_ + m];
  }
  float o = obj[b * N_ + n];
  float t = fminf(o * LOG2E, 80.f);
  float e2 = __builtin_amdgcn_exp2f(t);
  float sig = e2 * __builtin_amdgcn_rcpf(1.f + e2);
  float bce = (spa - xa) * (1.0f / (float)C_);
  float dice = 1.f - (2.f * sa + 1.f) / (ssa + ga + 1.f);
  cost[idx] = -2.f * sig + 5.f * bce + 5.f * dice;
}

#define BIGF 1e30f

// full-wave min via DPP (6 VALU ops), result broadcast via readlane(63)
__device__ __forceinline__ float wave_min_all(float x) {
  const int BI = __builtin_bit_cast(int, BIGF);
  int v = __builtin_bit_cast(int, x);
#define MIN_STEP(ctrl)                                                        \
  {                                                                           \
    int t_ = __builtin_amdgcn_update_dpp(BI, v, ctrl, 0xf, 0xf, false);       \
    v = __builtin_bit_cast(int, fminf(__builtin_bit_cast(float, v),           \
                                      __builtin_bit_cast(float, t_)));        \
  }
  MIN_STEP(0x111)  // row_shr:1
  MIN_STEP(0x112)  // row_shr:2
  MIN_STEP(0x114)  // row_shr:4
  MIN_STEP(0x118)  // row_shr:8
  MIN_STEP(0x142)  // row_bcast:15
  MIN_STEP(0x143)  // row_bcast:31
#undef MIN_STEP
  return __builtin_bit_cast(float, __builtin_amdgcn_readlane(v, 63));
}

__device__ __forceinline__ float rdlane_f(float x, int l) {
  return __builtin_bit_cast(float, __builtin_amdgcn_readlane(__builtin_bit_cast(int, x), l));
}

// JV LSAP on cost^T [32 x 128], one wave per batch. Lane owns cols 2*lane, 2*lane+1.
// All state in registers; cost in LDS (stride 129 = conflict-free).
__global__ __launch_bounds__(64) void lsap_kernel(const float* __restrict__ cost,
                                                  float* __restrict__ out)
{
  const int b = blockIdx.x;
  const int lane = threadIdx.x;
  __shared__ float cTs[M_ * 129];

#pragma unroll 4
  for (int t = 0; t < 16; ++t) {
    int e = t * 256 + lane * 4;
    float4 v4 = *(const float4*)&cost[b * 4096 + e];
    int n = e >> 5, m = e & 31;
    cTs[(m + 0) * 129 + n] = v4.x;
    cTs[(m + 1) * 129 + n] = v4.y;
    cTs[(m + 2) * 129 + n] = v4.z;
    cTs[(m + 3) * 129 + n] = v4.w;
  }
  __syncthreads();

  float u_reg = 0.f;      // u[lane], lane<32
  int c4r = -1;           // col4row[lane], lane<32
  float v0 = 0.f, v1 = 0.f;   // v[2*lane], v[2*lane+1]
  int r40 = -1, r41 = -1;     // row4col

  for (int cur = 0; cur < M_; ++cur) {
    float sh0 = BIGF, sh1 = BIGF;
    int p0 = -1, p1 = -1;
    bool sc0 = false, sc1 = false;
    unsigned srmask = 0u;
    int i = cur, sink = -1;
    float minVal = 0.f;

    while (sink < 0) {
      srmask |= 1u << i;
      float ui = rdlane_f(u_reg, i);
      float cc0 = cTs[i * 129 + 2 * lane];
      float cc1 = cTs[i * 129 + 2 * lane + 1];
      // match jnp associativity: ((minVal + c) - u[i]) - v
      float d0 = ((minVal + cc0) - ui) - v0;
      float d1 = ((minVal + cc1) - ui) - v1;
      if (!sc0 && d0 < sh0) { sh0 = d0; p0 = i; }
      if (!sc1 && d1 < sh1) { sh1 = d1; p1 = i; }
      float m0 = sc0 ? BIGF : sh0;
      float m1 = sc1 ? BIGF : sh1;
      float mv = wave_min_all(fminf(m0, m1));
      unsigned long long bl0 = __ballot(m0 == mv);
      unsigned long long bl1 = __ballot(m1 == mv);
      int j0 = bl0 ? 2 * (int)__builtin_ctzll(bl0) : 0x7fffffff;
      int j1 = bl1 ? 2 * (int)__builtin_ctzll(bl1) + 1 : 0x7fffffff;
      int j = j0 < j1 ? j0 : j1;   // first-index tie-break
      minVal = mv;
      if (lane == (j >> 1)) { if (j & 1) sc1 = true; else sc0 = true; }
      int nxt = __builtin_amdgcn_readlane((j & 1) ? r41 : r40, j >> 1);
      if (nxt < 0) sink = j; else i = nxt;
    }

    // dual updates (before augmentation, scipy order)
    int jj = c4r < 0 ? 0 : c4r;
    float g0 = __shfl(sh0, jj >> 1);
    float g1 = __shfl(sh1, jj >> 1);
    float sj = (jj & 1) ? g1 : g0;
    if (lane < M_) {
      if (lane == cur) u_reg += minVal;
      else if ((srmask >> lane) & 1u) u_reg += minVal - sj;
    }
    if (sc0) v0 -= minVal - sh0;
    if (sc1) v1 -= minVal - sh1;

    // augment along path
    int j = sink;
    while (true) {
      int i2 = __builtin_amdgcn_readlane((j & 1) ? p1 : p0, j >> 1);
      if (lane == (j >> 1)) { if (j & 1) r41 = i2; else r40 = i2; }
      int tmp = __builtin_amdgcn_readlane(c4r, i2);
      if (lane == i2) c4r = j;
      if (i2 == cur) break;
      j = tmp;
    }
  }
  if (lane < M_) out[b * M_ + lane] = (float)c4r;
}

extern "C" void kernel_launch(void* const* d_in, const int* in_sizes, int n_in,
                              void* d_out, int out_size, void* d_ws, size_t ws_size,
                              hipStream_t stream)
{
  const float* obj  = (const float*)d_in[0];   // [8,128]
  const float* pred = (const float*)d_in[1];   // [8,128,65536]
  const float* gt   = (const float*)d_in[2];   // [8,32,65536]
  float* out = (float*)d_out;                  // cost 32768 || indices 256 (as float)

  // per-(kc,b) partial slabs — no atomics, no memset needed
  float* xg_part  = (float*)d_ws;                       // 64*8*128*32 = 2,097,152
  float* sg_part  = xg_part + (size_t)KCHUNKS * B_ * N_ * M_;
  float* sp_part  = sg_part + (size_t)KCHUNKS * B_ * N_ * M_;  // 64*8*128
  float* ss_part  = sp_part + (size_t)KCHUNKS * B_ * N_;
  float* gts_part = ss_part + (size_t)KCHUNKS * B_ * N_;       // 64*8*32

  cost_partial_kernel<<<dim3(KCHUNKS, B_), 256, 0, stream>>>(
      pred, gt, xg_part, sg_part, sp_part, ss_part, gts_part);
  finalize_kernel<<<dim3(32768 / 64), 64, 0, stream>>>(
      obj, xg_part, sg_part, sp_part, ss_part, gts_part, out);
  lsap_kernel<<<dim3(B_), 64, 0, stream>>>(out, out + 32768);
}

// Round 3
// 569.950 us; speedup vs baseline: 1.0022x; 1.0022x over previous
//
#include <hip/hip_runtime.h>
#include <hip/hip_bf16.h>

#define LOG2E 1.4426950408889634f
#define LN2   0.6931471805599453f

typedef __attribute__((ext_vector_type(8))) short short8;
typedef __attribute__((ext_vector_type(4))) float f32x4;

#define B_ 8
#define N_ 128
#define M_ 32
#define C_ 65536
#define KCHUNKS 128
#define KC (C_ / KCHUNKS)   // 512
#define KSTEPS (KC / 32)    // 16

// Native bf16 RNE casts (m240: plain casts beat manual RNE / asm cvt_pk).
__device__ __forceinline__ unsigned pack2(float lo, float hi) {
  union { __hip_bfloat16 h; unsigned short s; } a, b;
  a.h = __float2bfloat16(lo);
  b.h = __float2bfloat16(hi);
  return (unsigned)a.s | ((unsigned)b.s << 16);
}

__device__ __forceinline__ short8 mk8(unsigned a, unsigned b, unsigned c, unsigned d) {
  union { short8 v; unsigned u[4]; } r;
  r.u[0] = a; r.u[1] = b; r.u[2] = c; r.u[3] = d;
  return r.v;
}

// softplus+sigmoid on 8 pred values; emit bf16 A-fragments for x and s.
__device__ __forceinline__ void actpack(float4 a, float4 bq,
    float& spa, float& sra, short8& xf, short8& sf) {
  float xs[8] = {a.x, a.y, a.z, a.w, bq.x, bq.y, bq.z, bq.w};
  float sv[8];
#pragma unroll
  for (int e = 0; e < 8; ++e) {
    float x = xs[e];
    float t = fminf(x * LOG2E, 80.f);       // exp2 of large-neg is clean 0
    float e2 = __builtin_amdgcn_exp2f(t);
    float z = 1.f + e2;
    float s = e2 * __builtin_amdgcn_rcpf(z);
    spa += __builtin_amdgcn_logf(z);        // log2; *LN2 deferred to epilogue
    sra += s;
    sv[e] = s;
  }
  xf = mk8(pack2(xs[0], xs[1]), pack2(xs[2], xs[3]),
           pack2(xs[4], xs[5]), pack2(xs[6], xs[7]));
  sf = mk8(pack2(sv[0], sv[1]), pack2(sv[2], sv[3]),
           pack2(sv[4], sv[5]), pack2(sv[6], sv[7]));
}

__device__ __forceinline__ void btpack(float4 a, float4 bq, float& ga, short8& bf) {
  ga += a.x + a.y + a.z + a.w + bq.x + bq.y + bq.z + bq.w;
  bf = mk8(pack2(a.x, a.y), pack2(a.z, a.w),
           pack2(bq.x, bq.y), pack2(bq.z, bq.w));   // exact on {0,1}
}

// BARRIER-FREE fragment-direct cost kernel.
// Grid (KCHUNKS=128, B=8) x 128 threads (2 waves) = 1024 blocks, 4/CU,
// 8 waves/CU. Each wave owns a 64x32 output tile: A-fragments (pred rows,
// 8 consecutive ch/lane at row=lane&15, k=quad*8+e) and B-fragments (gt)
// are loaded STRAIGHT from global in MFMA layout -- no LDS, no
// __syncthreads, no vmcnt(0) drains. Activation in-register, pack to
// bf16, 16 MFMAs per 32-channel k-step. 1-deep register prefetch.
__global__ __launch_bounds__(128, 2) void cost_partial_kernel(
    const float* __restrict__ pred, const float* __restrict__ gt,
    float* __restrict__ xg_part, float* __restrict__ sg_part,
    float* __restrict__ sp_part, float* __restrict__ ss_part,
    float* __restrict__ gts_part)
{
  const int kc = blockIdx.x, b = blockIdx.y;
  const int tid = threadIdx.x;
  const int wave = tid >> 6, lane = tid & 63;
  const int quad = lane >> 4, lcol = lane & 15;
  const int c0 = kc * KC;
  const int slab = kc * B_ + b;
  const int wrow0 = wave * 64;

  const float* pA[4];
  const float* pB[2];
#pragma unroll
  for (int rt = 0; rt < 4; ++rt)
    pA[rt] = pred + ((size_t)b * N_ + wrow0 + rt * 16 + lcol) * C_ + c0 + quad * 8;
#pragma unroll
  for (int ct = 0; ct < 2; ++ct)
    pB[ct] = gt + ((size_t)b * M_ + ct * 16 + lcol) * C_ + c0 + quad * 8;

  f32x4 accx[4][2], accs[4][2];
#pragma unroll
  for (int rt = 0; rt < 4; ++rt)
#pragma unroll
    for (int ct = 0; ct < 2; ++ct) {
      accx[rt][ct] = (f32x4){0.f, 0.f, 0.f, 0.f};
      accs[rt][ct] = (f32x4){0.f, 0.f, 0.f, 0.f};
    }
  float spr[4] = {0.f, 0.f, 0.f, 0.f};
  float srr[4] = {0.f, 0.f, 0.f, 0.f};
  float gta[2] = {0.f, 0.f};

  // prefetch k-step 0
  float4 a0[4], a1[4], b0[2], b1[2];
#pragma unroll
  for (int rt = 0; rt < 4; ++rt) {
    a0[rt] = *(const float4*)(pA[rt]);
    a1[rt] = *(const float4*)(pA[rt] + 4);
  }
#pragma unroll
  for (int ct = 0; ct < 2; ++ct) {
    b0[ct] = *(const float4*)(pB[ct]);
    b1[ct] = *(const float4*)(pB[ct] + 4);
  }

  for (int kk = 0; kk < KSTEPS; ++kk) {
    float4 na0[4], na1[4], nb0[2], nb1[2];
    if (kk + 1 < KSTEPS) {
      const int cb = (kk + 1) * 32;
#pragma unroll
      for (int rt = 0; rt < 4; ++rt) {
        na0[rt] = *(const float4*)(pA[rt] + cb);
        na1[rt] = *(const float4*)(pA[rt] + cb + 4);
      }
#pragma unroll
      for (int ct = 0; ct < 2; ++ct) {
        nb0[ct] = *(const float4*)(pB[ct] + cb);
        nb1[ct] = *(const float4*)(pB[ct] + cb + 4);
      }
    }

    short8 xf[4], sf[4], bf[2];
#pragma unroll
    for (int rt = 0; rt < 4; ++rt)
      actpack(a0[rt], a1[rt], spr[rt], srr[rt], xf[rt], sf[rt]);
#pragma unroll
    for (int ct = 0; ct < 2; ++ct)
      btpack(b0[ct], b1[ct], gta[ct], bf[ct]);

#pragma unroll
    for (int rt = 0; rt < 4; ++rt)
#pragma unroll
      for (int ct = 0; ct < 2; ++ct) {
        accx[rt][ct] = __builtin_amdgcn_mfma_f32_16x16x32_bf16(xf[rt], bf[ct], accx[rt][ct], 0, 0, 0);
        accs[rt][ct] = __builtin_amdgcn_mfma_f32_16x16x32_bf16(sf[rt], bf[ct], accs[rt][ct], 0, 0, 0);
      }

    if (kk + 1 < KSTEPS) {
#pragma unroll
      for (int rt = 0; rt < 4; ++rt) { a0[rt] = na0[rt]; a1[rt] = na1[rt]; }
#pragma unroll
      for (int ct = 0; ct < 2; ++ct) { b0[ct] = nb0[ct]; b1[ct] = nb1[ct]; }
    }
  }

  // row sums: lanes {r, r+16, r+32, r+48} share pred row r of the tile
#pragma unroll
  for (int rt = 0; rt < 4; ++rt) {
    float v1 = spr[rt], v2 = srr[rt];
    v1 += __shfl_xor(v1, 16); v1 += __shfl_xor(v1, 32);
    v2 += __shfl_xor(v2, 16); v2 += __shfl_xor(v2, 32);
    if (quad == 0) {
      sp_part[slab * N_ + wrow0 + rt * 16 + lcol] = v1 * LN2;
      ss_part[slab * N_ + wrow0 + rt * 16 + lcol] = v2;
    }
  }
  if (wave == 0) {
#pragma unroll
    for (int ct = 0; ct < 2; ++ct) {
      float g = gta[ct];
      g += __shfl_xor(g, 16); g += __shfl_xor(g, 32);
      if (quad == 0) gts_part[slab * M_ + ct * 16 + lcol] = g;
    }
  }

  // GEMM partials: C/D layout col=lane&15, row=(lane>>4)*4+reg
#pragma unroll
  for (int rt = 0; rt < 4; ++rt)
#pragma unroll
    for (int ct = 0; ct < 2; ++ct)
#pragma unroll
      for (int reg = 0; reg < 4; ++reg) {
        int orow = wrow0 + rt * 16 + quad * 4 + reg;
        int ocol = ct * 16 + lcol;
        xg_part[((size_t)slab * N_ + orow) * M_ + ocol] = accx[rt][ct][reg];
        sg_part[((size_t)slab * N_ + orow) * M_ + ocol] = accs[rt][ct][reg];
      }
}

__global__ void finalize_kernel(const float* __restrict__ obj,
    const float* __restrict__ xg_part, const float* __restrict__ sg_part,
    const float* __restrict__ sp_part, const float* __restrict__ ss_part,
    const float* __restrict__ gts_part, float* __restrict__ cost)
{
  int idx = blockIdx.x * blockDim.x + threadIdx.x;  // [0, 32768)
  int b = idx >> 12;
  int n = (idx >> 5) & 127;
  int m = idx & 31;
  float xa = 0.f, sa = 0.f, spa = 0.f, ssa = 0.f, ga = 0.f;
#pragma unroll 4
  for (int kc = 0; kc < KCHUNKS; ++kc) {
    int slab = kc * B_ + b;
    xa  += xg_part[((size_t)slab * N_ + n) * M_ + m];
    sa  += sg_part[((size_t)slab * N_ + n) * M_ + m];
    spa += sp_part[slab * N_ + n];
    ssa += ss_part[slab * N_ + n];
    ga  += gts_part[slab * M_ + m];
  }
  float o = obj[b * N_ + n];
  float t = fminf(o * LOG2E, 80.f);
  float e2 = __builtin_amdgcn_exp2f(t);
  float sig = e2 * __builtin_amdgcn_rcpf(1.f + e2);
  float bce = (spa - xa) * (1.0f / (float)C_);
  float dice = 1.f - (2.f * sa + 1.f) / (ssa + ga + 1.f);
  cost[idx] = -2.f * sig + 5.f * bce + 5.f * dice;
}

#define BIGF 1e30f

// full-wave min via DPP (6 VALU ops), result broadcast via readlane(63)
__device__ __forceinline__ float wave_min_all(float x) {
  const int BI = __builtin_bit_cast(int, BIGF);
  int v = __builtin_bit_cast(int, x);
#define MIN_STEP(ctrl)                                                        \
  {                                                                           \
    int t_ = __builtin_amdgcn_update_dpp(BI, v, ctrl, 0xf, 0xf, false);       \
    v = __builtin_bit_cast(int, fminf(__builtin_bit_cast(float, v),           \
                                      __builtin_bit_cast(float, t_)));        \
  }
  MIN_STEP(0x111)  // row_shr:1
  MIN_STEP(0x112)  // row_shr:2
  MIN_STEP(0x114)  // row_shr:4
  MIN_STEP(0x118)  // row_shr:8
  MIN_STEP(0x142)  // row_bcast:15
  MIN_STEP(0x143)  // row_bcast:31
#undef MIN_STEP
  return __builtin_bit_cast(float, __builtin_amdgcn_readlane(v, 63));
}

__device__ __forceinline__ float rdlane_f(float x, int l) {
  return __builtin_bit_cast(float, __builtin_amdgcn_readlane(__builtin_bit_cast(int, x), l));
}

// JV LSAP on cost^T [32 x 128], one wave per batch. Lane owns cols 2*lane, 2*lane+1.
// All state in registers; cost in LDS (stride 129 = conflict-free).
__global__ __launch_bounds__(64) void lsap_kernel(const float* __restrict__ cost,
                                                  float* __restrict__ out)
{
  const int b = blockIdx.x;
  const int lane = threadIdx.x;
  __shared__ float cTs[M_ * 129];

#pragma unroll 4
  for (int t = 0; t < 16; ++t) {
    int e = t * 256 + lane * 4;
    float4 v4 = *(const float4*)&cost[b * 4096 + e];
    int n = e >> 5, m = e & 31;
    cTs[(m + 0) * 129 + n] = v4.x;
    cTs[(m + 1) * 129 + n] = v4.y;
    cTs[(m + 2) * 129 + n] = v4.z;
    cTs[(m + 3) * 129 + n] = v4.w;
  }
  __syncthreads();

  float u_reg = 0.f;      // u[lane], lane<32
  int c4r = -1;           // col4row[lane], lane<32
  float v0 = 0.f, v1 = 0.f;   // v[2*lane], v[2*lane+1]
  int r40 = -1, r41 = -1;     // row4col

  for (int cur = 0; cur < M_; ++cur) {
    float sh0 = BIGF, sh1 = BIGF;
    int p0 = -1, p1 = -1;
    bool sc0 = false, sc1 = false;
    unsigned srmask = 0u;
    int i = cur, sink = -1;
    float minVal = 0.f;

    while (sink < 0) {
      srmask |= 1u << i;
      float ui = rdlane_f(u_reg, i);
      float cc0 = cTs[i * 129 + 2 * lane];
      float cc1 = cTs[i * 129 + 2 * lane + 1];
      // match jnp associativity: ((minVal + c) - u[i]) - v
      float d0 = ((minVal + cc0) - ui) - v0;
      float d1 = ((minVal + cc1) - ui) - v1;
      if (!sc0 && d0 < sh0) { sh0 = d0; p0 = i; }
      if (!sc1 && d1 < sh1) { sh1 = d1; p1 = i; }
      float m0 = sc0 ? BIGF : sh0;
      float m1 = sc1 ? BIGF : sh1;
      float mv = wave_min_all(fminf(m0, m1));
      unsigned long long bl0 = __ballot(m0 == mv);
      unsigned long long bl1 = __ballot(m1 == mv);
      int j0 = bl0 ? 2 * (int)__builtin_ctzll(bl0) : 0x7fffffff;
      int j1 = bl1 ? 2 * (int)__builtin_ctzll(bl1) + 1 : 0x7fffffff;
      int j = j0 < j1 ? j0 : j1;   // first-index tie-break
      minVal = mv;
      if (lane == (j >> 1)) { if (j & 1) sc1 = true; else sc0 = true; }
      int nxt = __builtin_amdgcn_readlane((j & 1) ? r41 : r40, j >> 1);
      if (nxt < 0) sink = j; else i = nxt;
    }

    // dual updates (before augmentation, scipy order)
    int jj = c4r < 0 ? 0 : c4r;
    float g0 = __shfl(sh0, jj >> 1);
    float g1 = __shfl(sh1, jj >> 1);
    float sj = (jj & 1) ? g1 : g0;
    if (lane < M_) {
      if (lane == cur) u_reg += minVal;
      else if ((srmask >> lane) & 1u) u_reg += minVal - sj;
    }
    if (sc0) v0 -= minVal - sh0;
    if (sc1) v1 -= minVal - sh1;

    // augment along path
    int j = sink;
    while (true) {
      int i2 = __builtin_amdgcn_readlane((j & 1) ? p1 : p0, j >> 1);
      if (lane == (j >> 1)) { if (j & 1) r41 = i2; else r40 = i2; }
      int tmp = __builtin_amdgcn_readlane(c4r, i2);
      if (lane == i2) c4r = j;
      if (i2 == cur) break;
      j = tmp;
    }
  }
  if (lane < M_) out[b * M_ + lane] = (float)c4r;
}

extern "C" void kernel_launch(void* const* d_in, const int* in_sizes, int n_in,
                              void* d_out, int out_size, void* d_ws, size_t ws_size,
                              hipStream_t stream)
{
  const float* obj  = (const float*)d_in[0];   // [8,128]
  const float* pred = (const float*)d_in[1];   // [8,128,65536]
  const float* gt   = (const float*)d_in[2];   // [8,32,65536]
  float* out = (float*)d_out;                  // cost 32768 || indices 256 (as float)

  // per-(kc,b) partial slabs — no atomics, no memset needed
  float* xg_part  = (float*)d_ws;                       // 128*8*128*32 = 4,194,304
  float* sg_part  = xg_part + (size_t)KCHUNKS * B_ * N_ * M_;
  float* sp_part  = sg_part + (size_t)KCHUNKS * B_ * N_ * M_;  // 128*8*128
  float* ss_part  = sp_part + (size_t)KCHUNKS * B_ * N_;
  float* gts_part = ss_part + (size_t)KCHUNKS * B_ * N_;       // 128*8*32

  cost_partial_kernel<<<dim3(KCHUNKS, B_), 128, 0, stream>>>(
      pred, gt, xg_part, sg_part, sp_part, ss_part, gts_part);
  finalize_kernel<<<dim3(32768 / 64), 64, 0, stream>>>(
      obj, xg_part, sg_part, sp_part, ss_part, gts_part, out);
  lsap_kernel<<<dim3(B_), 64, 0, stream>>>(out, out + 32768);
}